// Round 4
// baseline (461.029 us; speedup 1.0000x reference)
//
#include <hip/hip_runtime.h>
#include <math.h>

typedef __bf16 bf16_t;
typedef bf16_t bf16x8 __attribute__((ext_vector_type(8)));
typedef float floatx4 __attribute__((ext_vector_type(4)));

#define MFMA(a, b, c) __builtin_amdgcn_mfma_f32_16x16x32_bf16(a, b, c, 0, 0, 0)

static constexpr int S = 2048, E = 4096, H = 128;

__device__ __forceinline__ void gl_lds16(const void* g, void* l) {
  __builtin_amdgcn_global_load_lds((const __attribute__((address_space(1))) void*)g,
                                   (__attribute__((address_space(3))) void*)l,
                                   16, 0, 0);
}

// ---------------------------------------------------------------------------
// Kernel 1: W transpose + fp32->bf16.  Wt[w*128+h][e] = W_w[e][h]
// ---------------------------------------------------------------------------
__global__ __launch_bounds__(256) void wt_kernel(const float* __restrict__ Wq,
                                                 const float* __restrict__ Wk,
                                                 const float* __restrict__ Wv,
                                                 bf16_t* __restrict__ Wt) {
  __shared__ bf16_t tile[64][130];
  int wb = blockIdx.x / 64;
  int eb = blockIdx.x % 64;
  const float* W = wb == 0 ? Wq : (wb == 1 ? Wk : Wv);
  int t = threadIdx.x;
  {
    int er = t >> 2, q = t & 3;
    const float4* src = (const float4*)(W + (size_t)(eb * 64 + er) * H + q * 32);
    for (int i = 0; i < 8; ++i) {
      float4 f = src[i];
      int c = q * 32 + i * 4;
      tile[er][c + 0] = (bf16_t)f.x; tile[er][c + 1] = (bf16_t)f.y;
      tile[er][c + 2] = (bf16_t)f.z; tile[er][c + 3] = (bf16_t)f.w;
    }
  }
  __syncthreads();
  {
    int h = t >> 1, half = t & 1;
    bf16_t buf[32];
    for (int j = 0; j < 32; ++j) buf[j] = tile[half * 32 + j][h];
    bf16_t* dst = Wt + (size_t)(wb * H + h) * E + eb * 64 + half * 32;
    for (int i = 0; i < 4; ++i) ((uint4*)dst)[i] = ((uint4*)buf)[i];
  }
}

// ---------------------------------------------------------------------------
// Kernel 2: QKV projection, merged 64m x 384n tile, BK=64 dbuf, 256 blocks
// (1/CU), 512 threads.  Counted-vmcnt pipeline with DEPTH-2 X prefetch:
// the X set consumed by STAGE_X was loaded ~2 phases earlier (xo/xe sets,
// loads issued one phase ahead of R3) -> STAGE_X never stalls on HBM.
// WAITB(2) keeps the trailing X loads in flight across the barrier.
// XOR-8 granule swizzle on 128 B rows: LDS[row][g] = Global[row][g^(row&7)].
// ---------------------------------------------------------------------------
__global__ __launch_bounds__(512, 2) void qkv_kernel(const float* __restrict__ X,
                                                     const bf16_t* __restrict__ Wt,
                                                     bf16_t* __restrict__ Qb,
                                                     bf16_t* __restrict__ Kb,
                                                     bf16_t* __restrict__ Vt) {
  // buf0: X [0,8K) W [8K,56K) | buf1: X [56K,64K) W [64K,112K)
  __shared__ __align__(16) char smem[114688];
  constexpr int B0X = 0, B0W = 8192, B1X = 57344, B1W = 65536;

  int mBase = blockIdx.x * 64;
  int t = threadIdx.x, lane = t & 63, w = t >> 6;
  int r16 = lane & 15, q4 = lane >> 4;

  floatx4 acc[4][3] = {};

  // X global: row = t>>3 (8 thr/row), two 16B chunks at cols (t&7)*4, +32
  int xrow = t >> 3;
  const float* xbase = X + (size_t)(mBase + xrow) * E + (t & 7) * 4;
  int wrl = lane >> 3, wg = lane & 7;  // W staging: 8 rows / gl_lds issue

  float4 xo[2], xe[2];

#define FENCE() asm volatile("" ::: "memory")
#define WAITB(N)                                                                 \
  do {                                                                           \
    asm volatile("s_waitcnt vmcnt(" #N ") lgkmcnt(0)" ::: "memory");             \
    __builtin_amdgcn_s_barrier();                                                \
    asm volatile("" ::: "memory");                                               \
  } while (0)

#define LOAD_X(XR, K0)                                                           \
  _Pragma("unroll") for (int i = 0; i < 2; ++i)                                  \
      (XR)[i] = *(const float4*)(xbase + (K0) + i * 32);

#define STAGE_W(WOFF, K0)                                                        \
  _Pragma("unroll") for (int is = 0; is < 6; ++is) {                             \
    int row = w * 48 + is * 8 + wrl;                                             \
    int g = wg ^ (row & 7);                                                      \
    gl_lds16(Wt + (size_t)row * E + (K0) + g * 8,                                \
             smem + (WOFF) + (w * 48 + is * 8) * 128 + lane * 16);               \
  }

#define STAGE_X(XOFF, XR)                                                        \
  _Pragma("unroll") for (int i = 0; i < 2; ++i) {                                \
    float4 f = (XR)[i];                                                          \
    bf16_t pk[4] = {(bf16_t)f.x, (bf16_t)f.y, (bf16_t)f.z, (bf16_t)f.w};         \
    int gc = ((t & 7) >> 1) + i * 4;                                             \
    int g = gc ^ (xrow & 7);                                                     \
    *(uint2*)(smem + (XOFF) + xrow * 128 + g * 16 + (t & 1) * 8) = *(uint2*)pk;  \
  }

#define COMPUTE(XOFF, WOFF)                                                      \
  __builtin_amdgcn_s_setprio(1);                                                 \
  _Pragma("unroll") for (int kc = 0; kc < 2; ++kc) {                             \
    bf16x8 a[4], b[3];                                                           \
    _Pragma("unroll") for (int i = 0; i < 4; ++i) {                              \
      int row = i * 16 + r16;                                                    \
      int sl = (kc * 4 + q4) ^ (row & 7);                                        \
      a[i] = *(const bf16x8*)(smem + (XOFF) + row * 128 + sl * 16);              \
    }                                                                            \
    _Pragma("unroll") for (int j = 0; j < 3; ++j) {                              \
      int row = w * 48 + j * 16 + r16;                                           \
      int sl = (kc * 4 + q4) ^ (row & 7);                                        \
      b[j] = *(const bf16x8*)(smem + (WOFF) + row * 128 + sl * 16);              \
    }                                                                            \
    _Pragma("unroll") for (int i = 0; i < 4; ++i)                                \
        _Pragma("unroll") for (int j = 0; j < 3; ++j)                            \
            acc[i][j] = MFMA(a[i], b[j], acc[i][j]);                             \
  }                                                                              \
  __builtin_amdgcn_s_setprio(0);

  // prologue: tile0 -> buf0; X(1)->xo, X(2)->xe stay in flight
  LOAD_X(xe, 0);
  FENCE();
  STAGE_W(B0W, 0);
  FENCE();
  STAGE_X(B0X, xe);  // waits xe loads only (oldest)
  FENCE();
  LOAD_X(xo, 64);
  LOAD_X(xe, 128);
  WAITB(4);

  for (int kb = 0; kb < 62; kb += 2) {
    // phase A: compute tile kb (buf0); stage kb+1 -> buf1 (from xo, loaded
    // 2 phases ago); load xo = X(kb+3)
    STAGE_W(B1W, (kb + 1) * 64);
    FENCE();
    STAGE_X(B1X, xo);
    FENCE();
    LOAD_X(xo, (kb + 3) * 64);
    FENCE();
    COMPUTE(B0X, B0W);
    WAITB(2);

    // phase B: compute tile kb+1 (buf1); stage kb+2 -> buf0 (from xe);
    // load xe = X(kb+4) while kb+4 <= 63
    STAGE_W(B0W, (kb + 2) * 64);
    FENCE();
    STAGE_X(B0X, xe);
    FENCE();
    if (kb < 60) {
      LOAD_X(xe, (kb + 4) * 64);
      FENCE();
      COMPUTE(B1X, B1W);
      WAITB(2);
    } else {
      COMPUTE(B1X, B1W);
      WAITB(0);
    }
  }
  // tail: buf0 = tile 62; stage tile 63 from xo (= X(63))
  STAGE_W(B1W, 63 * 64);
  FENCE();
  STAGE_X(B1X, xo);
  FENCE();
  COMPUTE(B0X, B0W);
  WAITB(0);
  COMPUTE(B1X, B1W);

  // ---- epilogue ----
  int bb = mBase >> 11, sBase = mBase & 2047;
  bf16_t(*Ob)[264] = (bf16_t(*)[264])smem;
#pragma unroll
  for (int i = 0; i < 4; ++i)
#pragma unroll
    for (int j = 0; j < 3; ++j) {
      int ncol = w * 48 + j * 16;
      if (ncol >= 256) {
        int h = ncol - 256 + r16;
        bf16_t pk[4];
#pragma unroll
        for (int ii = 0; ii < 4; ++ii) pk[ii] = (bf16_t)acc[i][j][ii];
        *(uint2*)&Vt[((size_t)bb * H + h) * S + sBase + i * 16 + q4 * 4] =
            *(uint2*)pk;
      } else {
#pragma unroll
        for (int ii = 0; ii < 4; ++ii)
          Ob[i * 16 + q4 * 4 + ii][ncol + r16] = (bf16_t)acc[i][j][ii];
      }
    }
  __syncthreads();
  {
    int row = t >> 3, g = t & 7;
    bf16_t* qp = Qb + (size_t)(mBase + row) * H + g * 16;
    bf16_t* kp = Kb + (size_t)(mBase + row) * H + g * 16;
    *(uint4*)qp = *(uint4*)&Ob[row][g * 16];
    *(uint4*)(qp + 8) = *(uint4*)&Ob[row][g * 16 + 8];
    *(uint4*)kp = *(uint4*)&Ob[row][128 + g * 16];
    *(uint4*)(kp + 8) = *(uint4*)&Ob[row][128 + g * 16 + 8];
  }
#undef LOAD_X
#undef STAGE_W
#undef STAGE_X
#undef COMPUTE
#undef FENCE
#undef WAITB
}

// ---------------------------------------------------------------------------
// Kernel 3: flash attention partials. 512 blocks x 256 thr (2/CU); block =
// (b, qt, key-half): 64 q-rows x 1024 keys.  K/V double-buffered; stage
// it+1 issued before compute(it), drained by the end-of-iter barrier.
// Softmax: T13 defer-max (THR=8; lane-local partial max vs m_r, __all ->
// skip max-reduce + rescale entirely) and l-sum via MFMA P*ones (replaces
// the 4-deep shfl_xor sum chain).  Exact w.r.t. the merge step: m is only
// an exp offset; P bounded by e^8.
// ---------------------------------------------------------------------------
__global__ __launch_bounds__(256, 2) void attn_kernel(const bf16_t* __restrict__ Qb,
                                                      const bf16_t* __restrict__ Kb,
                                                      const bf16_t* __restrict__ Vt,
                                                      float* __restrict__ Op,
                                                      float* __restrict__ Mp,
                                                      float* __restrict__ Lp) {
  // buf0: K [0,16K) V [16K,32K) | buf1: K [32K,48K) V [48K,64K) | P [64K,73K)
  __shared__ __align__(16) char smem[74752];

  int bid = blockIdx.x;
  int b = bid & 7, r = bid >> 3;
  int qt = r >> 1, half = r & 1;

  int t = threadIdx.x, lane = t & 63, wl = t >> 6;
  int r16 = lane & 15, q4 = lane >> 4;
  bf16_t(*Pl)[72] = (bf16_t(*)[72])(smem + 65536 + wl * 2304);

  bf16x8 qf[4];
  {
    const bf16_t* qp = Qb + (size_t)(b * S + qt * 64 + wl * 16 + r16) * H + q4 * 8;
#pragma unroll
    for (int c = 0; c < 4; ++c) qf[c] = *(const bf16x8*)(qp + c * 32);
  }
  bf16x8 onef;
#pragma unroll
  for (int i = 0; i < 8; ++i) onef[i] = (bf16_t)1.0f;

  floatx4 o[8] = {};
  float m_r[4], l_r[4];
#pragma unroll
  for (int ii = 0; ii < 4; ++ii) { m_r[ii] = -1e30f; l_r[ii] = 0.f; }
  const float scale = 0.08838834764831845f;  // 1/sqrt(128)

  int kr = lane >> 4, kg = lane & 15;
  int vr = lane >> 3, vg = lane & 7;

#define STAGE_KV(BUF, KT)                                                        \
  _Pragma("unroll") for (int is = 0; is < 4; ++is) {                             \
    int row = wl * 16 + is * 4 + kr;                                             \
    int g = kg ^ (row & 15);                                                     \
    gl_lds16(Kb + (size_t)(b * S + (KT) * 64 + row) * H + g * 8,                 \
             smem + (BUF) + (wl * 16 + is * 4) * 256 + lane * 16);               \
  }                                                                              \
  _Pragma("unroll") for (int is = 0; is < 4; ++is) {                             \
    int row = wl * 32 + is * 8 + vr;                                             \
    int g = vg ^ (row & 7);                                                      \
    gl_lds16(Vt + (size_t)(b * H + row) * S + (KT) * 64 + g * 8,                 \
             smem + (BUF) + 16384 + (wl * 32 + is * 8) * 128 + lane * 16);       \
  }

  STAGE_KV(0, half * 16);
  __syncthreads();

  for (int it = 0; it < 16; ++it) {
    int cur = (it & 1) << 15;  // 0 or 32768
    if (it < 15) { STAGE_KV(cur ^ 32768, half * 16 + it + 1); }
    const char* kbase = smem + cur;
    bf16_t(*Vl)[64] = (bf16_t(*)[64])(smem + cur + 16384);

    // S = Q K^T   (Kl slot key = r16, conflict-free)
    floatx4 s4[4] = {};
    __builtin_amdgcn_s_setprio(1);
#pragma unroll
    for (int c = 0; c < 4; ++c)
#pragma unroll
      for (int j = 0; j < 4; ++j) {
        int row = j * 16 + r16;
        int sl = (c * 4 + q4) ^ r16;
        bf16x8 bk = *(const bf16x8*)(kbase + row * 256 + sl * 16);
        s4[j] = MFMA(qf[c], bk, s4[j]);
      }
    __builtin_amdgcn_s_setprio(0);

    // softmax, defer-max: lane-local partial max vs m_r + 8
    float p[4][4], mxl[4];
#pragma unroll
    for (int ii = 0; ii < 4; ++ii) mxl[ii] = -1e30f;
#pragma unroll
    for (int j = 0; j < 4; ++j)
#pragma unroll
      for (int ii = 0; ii < 4; ++ii) {
        float sv = s4[j][ii] * scale;
        p[j][ii] = sv;
        mxl[ii] = fmaxf(mxl[ii], sv);
      }
    int ok = 1;
#pragma unroll
    for (int ii = 0; ii < 4; ++ii) ok &= (mxl[ii] <= m_r[ii] + 8.f) ? 1 : 0;
    if (!__all(ok)) {
      // rare path: full max-reduce over the r16 group + rescale
      float alpha[4];
#pragma unroll
      for (int off = 1; off <= 8; off <<= 1)
#pragma unroll
        for (int ii = 0; ii < 4; ++ii)
          mxl[ii] = fmaxf(mxl[ii], __shfl_xor(mxl[ii], off));
#pragma unroll
      for (int ii = 0; ii < 4; ++ii) {
        float mn = fmaxf(m_r[ii], mxl[ii]);
        alpha[ii] = __expf(m_r[ii] - mn);
        m_r[ii] = mn;
        l_r[ii] *= alpha[ii];
      }
#pragma unroll
      for (int f = 0; f < 8; ++f)
#pragma unroll
        for (int ii = 0; ii < 4; ++ii) o[f][ii] *= alpha[ii];
    }
#pragma unroll
    for (int j = 0; j < 4; ++j)
#pragma unroll
      for (int ii = 0; ii < 4; ++ii) {
        float e = __expf(p[j][ii] - m_r[ii]);
        Pl[q4 * 4 + ii][j * 16 + r16] = (bf16_t)e;  // per-wave, in-order DS
      }

    // O += P V ; l += P * ones (MFMA row-sum, D-layout matches l_r[ii])
    bf16x8 pa0 = *(const bf16x8*)&Pl[r16][q4 * 8];
    bf16x8 pa1 = *(const bf16x8*)&Pl[r16][32 + q4 * 8];
    __builtin_amdgcn_s_setprio(1);
    floatx4 lsv = {};
    lsv = MFMA(pa0, onef, lsv);
    lsv = MFMA(pa1, onef, lsv);
#pragma unroll
    for (int f = 0; f < 8; ++f) {
      int row = f * 16 + r16;
      int sl = q4 ^ (row & 7);
      o[f] = MFMA(pa0, *(const bf16x8*)&Vl[row][sl * 8], o[f]);
    }
#pragma unroll
    for (int f = 0; f < 8; ++f) {
      int row = f * 16 + r16;
      int sl = (4 + q4) ^ (row & 7);
      o[f] = MFMA(pa1, *(const bf16x8*)&Vl[row][sl * 8], o[f]);
    }
    __builtin_amdgcn_s_setprio(0);
#pragma unroll
    for (int ii = 0; ii < 4; ++ii) l_r[ii] += lsv[ii];
    __syncthreads();
  }
#undef STAGE_KV

  // write unnormalized partials
  int rowg = b * S + qt * 64 + wl * 16 + q4 * 4;
  float* op = Op + ((size_t)half * 16384 + rowg) * 128;
#pragma unroll
  for (int f = 0; f < 8; ++f)
#pragma unroll
    for (int ii = 0; ii < 4; ++ii)
      op[ii * 128 + f * 16 + r16] = o[f][ii];
  if (r16 == 0) {
#pragma unroll
    for (int ii = 0; ii < 4; ++ii) {
      Mp[half * 16384 + rowg + ii] = m_r[ii];
      Lp[half * 16384 + rowg + ii] = l_r[ii];
    }
  }
}

// ---------------------------------------------------------------------------
// Kernel 4: merge the two key-half partials -> final output.
// ---------------------------------------------------------------------------
__global__ __launch_bounds__(256) void merge_kernel(const float* __restrict__ Op,
                                                    const float* __restrict__ Mp,
                                                    const float* __restrict__ Lp,
                                                    float* __restrict__ out) {
  int t = threadIdx.x;
  int row = blockIdx.x * 64 + (t >> 2);
  int c0 = (t & 3) * 32;
  float m1 = Mp[row], m2 = Mp[16384 + row];
  float l1 = Lp[row], l2 = Lp[16384 + row];
  float M = fmaxf(m1, m2);
  float e1 = __expf(m1 - M), e2 = __expf(m2 - M);
  float inv = 1.f / (e1 * l1 + e2 * l2);
  const float4* o1 = (const float4*)(Op + (size_t)row * 128 + c0);
  const float4* o2 = (const float4*)(Op + 16384ull * 128 + (size_t)row * 128 + c0);
  float4* op = (float4*)(out + (size_t)row * 128 + c0);
#pragma unroll
  for (int i = 0; i < 8; ++i) {
    float4 a = o1[i], b = o2[i];
    float4 rr;
    rr.x = (e1 * a.x + e2 * b.x) * inv;
    rr.y = (e1 * a.y + e2 * b.y) * inv;
    rr.z = (e1 * a.z + e2 * b.z) * inv;
    rr.w = (e1 * a.w + e2 * b.w) * inv;
    op[i] = rr;
  }
}

// ---------------------------------------------------------------------------
extern "C" void kernel_launch(void* const* d_in, const int* in_sizes, int n_in,
                              void* d_out, int out_size, void* d_ws, size_t ws_size,
                              hipStream_t stream) {
  const float* x = (const float*)d_in[0];
  const float* Wq = (const float*)d_in[1];
  const float* Wk = (const float*)d_in[2];
  const float* Wv = (const float*)d_in[3];
  float* out = (float*)d_out;

  // ws (bf16): Wt [384][4096] | Qb [16384][128] | Kb | Vt [8][128][2048]
  // then (f32): Op [2][16384][128] | Mp [2][16384] | Lp [2][16384]
  bf16_t* Wt = (bf16_t*)d_ws;
  bf16_t* Qb = Wt + (size_t)384 * 4096;
  bf16_t* Kb = Qb + (size_t)16384 * 128;
  bf16_t* Vt = Kb + (size_t)16384 * 128;
  float* Op = (float*)(Vt + (size_t)8 * 128 * 2048);
  float* Mp = Op + (size_t)2 * 16384 * 128;
  float* Lp = Mp + 2 * 16384;

  wt_kernel<<<192, 256, 0, stream>>>(Wq, Wk, Wv, Wt);
  qkv_kernel<<<256, 512, 0, stream>>>(x, Wt, Qb, Kb, Vt);
  attn_kernel<<<512, 256, 0, stream>>>(Qb, Kb, Vt, Op, Mp, Lp);
  merge_kernel<<<256, 256, 0, stream>>>(Op, Mp, Lp, out);
}

// Round 5
// 435.280 us; speedup vs baseline: 1.0592x; 1.0592x over previous
//
#include <hip/hip_runtime.h>
#include <math.h>

typedef __bf16 bf16_t;
typedef bf16_t bf16x8 __attribute__((ext_vector_type(8)));
typedef float floatx4 __attribute__((ext_vector_type(4)));

#define MFMA(a, b, c) __builtin_amdgcn_mfma_f32_16x16x32_bf16(a, b, c, 0, 0, 0)

static constexpr int S = 2048, E = 4096, H = 128;

__device__ __forceinline__ void gl_lds16(const void* g, void* l) {
  __builtin_amdgcn_global_load_lds((const __attribute__((address_space(1))) void*)g,
                                   (__attribute__((address_space(3))) void*)l,
                                   16, 0, 0);
}

// ---------------------------------------------------------------------------
// Kernel 1: W transpose + fp32->bf16.  Wt[w*128+h][e] = W_w[e][h]
// ---------------------------------------------------------------------------
__global__ __launch_bounds__(256) void wt_kernel(const float* __restrict__ Wq,
                                                 const float* __restrict__ Wk,
                                                 const float* __restrict__ Wv,
                                                 bf16_t* __restrict__ Wt) {
  __shared__ bf16_t tile[64][130];
  int wb = blockIdx.x / 64;
  int eb = blockIdx.x % 64;
  const float* W = wb == 0 ? Wq : (wb == 1 ? Wk : Wv);
  int t = threadIdx.x;
  {
    int er = t >> 2, q = t & 3;
    const float4* src = (const float4*)(W + (size_t)(eb * 64 + er) * H + q * 32);
    for (int i = 0; i < 8; ++i) {
      float4 f = src[i];
      int c = q * 32 + i * 4;
      tile[er][c + 0] = (bf16_t)f.x; tile[er][c + 1] = (bf16_t)f.y;
      tile[er][c + 2] = (bf16_t)f.z; tile[er][c + 3] = (bf16_t)f.w;
    }
  }
  __syncthreads();
  {
    int h = t >> 1, half = t & 1;
    bf16_t buf[32];
    for (int j = 0; j < 32; ++j) buf[j] = tile[half * 32 + j][h];
    bf16_t* dst = Wt + (size_t)(wb * H + h) * E + eb * 64 + half * 32;
    for (int i = 0; i < 4; ++i) ((uint4*)dst)[i] = ((uint4*)buf)[i];
  }
}

// ---------------------------------------------------------------------------
// Kernel 2: QKV projection, merged 64m x 384n tile, BK=64 dbuf, 256 blocks
// (1/CU), 512 threads.  X loads are NON-TEMPORAL (nt bit, evict-first):
// X streams 256 MB with zero reuse and was evicting the 3 MB Wt from the
// per-XCD L2, forcing the 768 MB logical W refetch to be served from L3
// (~the whole 160 us wall).  With nt-X, Wt stays L2-resident and the W
// gl_lds traffic is served at L2 BW; qkv's floor drops to the X HBM stream.
// Counted-vmcnt pipeline with depth-2 X prefetch; WAITB(2) keeps trailing
// X loads in flight across the barrier.
// XOR-8 granule swizzle on 128 B rows: LDS[row][g] = Global[row][g^(row&7)].
// ---------------------------------------------------------------------------
__global__ __launch_bounds__(512, 2) void qkv_kernel(const float* __restrict__ X,
                                                     const bf16_t* __restrict__ Wt,
                                                     bf16_t* __restrict__ Qb,
                                                     bf16_t* __restrict__ Kb,
                                                     bf16_t* __restrict__ Vt) {
  // buf0: X [0,8K) W [8K,56K) | buf1: X [56K,64K) W [64K,112K)
  __shared__ __align__(16) char smem[114688];
  constexpr int B0X = 0, B0W = 8192, B1X = 57344, B1W = 65536;

  int mBase = blockIdx.x * 64;
  int t = threadIdx.x, lane = t & 63, w = t >> 6;
  int r16 = lane & 15, q4 = lane >> 4;

  floatx4 acc[4][3] = {};

  // X global: row = t>>3 (8 thr/row), two 16B chunks at cols (t&7)*4, +32
  int xrow = t >> 3;
  const float* xbase = X + (size_t)(mBase + xrow) * E + (t & 7) * 4;
  int wrl = lane >> 3, wg = lane & 7;  // W staging: 8 rows / gl_lds issue

  floatx4 xo[2], xe[2];

#define FENCE() asm volatile("" ::: "memory")
#define WAITB(N)                                                                 \
  do {                                                                           \
    asm volatile("s_waitcnt vmcnt(" #N ") lgkmcnt(0)" ::: "memory");             \
    __builtin_amdgcn_s_barrier();                                                \
    asm volatile("" ::: "memory");                                               \
  } while (0)

#define LOAD_X(XR, K0)                                                           \
  _Pragma("unroll") for (int i = 0; i < 2; ++i)                                  \
      (XR)[i] = __builtin_nontemporal_load(                                      \
          (const floatx4*)(xbase + (K0) + i * 32));

#define STAGE_W(WOFF, K0)                                                        \
  _Pragma("unroll") for (int is = 0; is < 6; ++is) {                             \
    int row = w * 48 + is * 8 + wrl;                                             \
    int g = wg ^ (row & 7);                                                      \
    gl_lds16(Wt + (size_t)row * E + (K0) + g * 8,                                \
             smem + (WOFF) + (w * 48 + is * 8) * 128 + lane * 16);               \
  }

#define STAGE_X(XOFF, XR)                                                        \
  _Pragma("unroll") for (int i = 0; i < 2; ++i) {                                \
    floatx4 f = (XR)[i];                                                         \
    bf16_t pk[4] = {(bf16_t)f[0], (bf16_t)f[1], (bf16_t)f[2], (bf16_t)f[3]};     \
    int gc = ((t & 7) >> 1) + i * 4;                                             \
    int g = gc ^ (xrow & 7);                                                     \
    *(uint2*)(smem + (XOFF) + xrow * 128 + g * 16 + (t & 1) * 8) = *(uint2*)pk;  \
  }

#define COMPUTE(XOFF, WOFF)                                                      \
  __builtin_amdgcn_s_setprio(1);                                                 \
  _Pragma("unroll") for (int kc = 0; kc < 2; ++kc) {                             \
    bf16x8 a[4], b[3];                                                           \
    _Pragma("unroll") for (int i = 0; i < 4; ++i) {                              \
      int row = i * 16 + r16;                                                    \
      int sl = (kc * 4 + q4) ^ (row & 7);                                        \
      a[i] = *(const bf16x8*)(smem + (XOFF) + row * 128 + sl * 16);              \
    }                                                                            \
    _Pragma("unroll") for (int j = 0; j < 3; ++j) {                              \
      int row = w * 48 + j * 16 + r16;                                           \
      int sl = (kc * 4 + q4) ^ (row & 7);                                        \
      b[j] = *(const bf16x8*)(smem + (WOFF) + row * 128 + sl * 16);              \
    }                                                                            \
    _Pragma("unroll") for (int i = 0; i < 4; ++i)                                \
        _Pragma("unroll") for (int j = 0; j < 3; ++j)                            \
            acc[i][j] = MFMA(a[i], b[j], acc[i][j]);                             \
  }                                                                              \
  __builtin_amdgcn_s_setprio(0);

  // prologue: tile0 -> buf0; X(1)->xo, X(2)->xe stay in flight
  LOAD_X(xe, 0);
  FENCE();
  STAGE_W(B0W, 0);
  FENCE();
  STAGE_X(B0X, xe);  // waits xe loads only (oldest)
  FENCE();
  LOAD_X(xo, 64);
  LOAD_X(xe, 128);
  WAITB(4);

  for (int kb = 0; kb < 62; kb += 2) {
    // phase A: compute tile kb (buf0); stage kb+1 -> buf1 (from xo, loaded
    // 2 phases ago); load xo = X(kb+3)
    STAGE_W(B1W, (kb + 1) * 64);
    FENCE();
    STAGE_X(B1X, xo);
    FENCE();
    LOAD_X(xo, (kb + 3) * 64);
    FENCE();
    COMPUTE(B0X, B0W);
    WAITB(2);

    // phase B: compute tile kb+1 (buf1); stage kb+2 -> buf0 (from xe);
    // load xe = X(kb+4) while kb+4 <= 63
    STAGE_W(B0W, (kb + 2) * 64);
    FENCE();
    STAGE_X(B0X, xe);
    FENCE();
    if (kb < 60) {
      LOAD_X(xe, (kb + 4) * 64);
      FENCE();
      COMPUTE(B1X, B1W);
      WAITB(2);
    } else {
      COMPUTE(B1X, B1W);
      WAITB(0);
    }
  }
  // tail: buf0 = tile 62; stage tile 63 from xo (= X(63))
  STAGE_W(B1W, 63 * 64);
  FENCE();
  STAGE_X(B1X, xo);
  FENCE();
  COMPUTE(B0X, B0W);
  WAITB(0);
  COMPUTE(B1X, B1W);

  // ---- epilogue ----
  int bb = mBase >> 11, sBase = mBase & 2047;
  bf16_t(*Ob)[264] = (bf16_t(*)[264])smem;
#pragma unroll
  for (int i = 0; i < 4; ++i)
#pragma unroll
    for (int j = 0; j < 3; ++j) {
      int ncol = w * 48 + j * 16;
      if (ncol >= 256) {
        int h = ncol - 256 + r16;
        bf16_t pk[4];
#pragma unroll
        for (int ii = 0; ii < 4; ++ii) pk[ii] = (bf16_t)acc[i][j][ii];
        *(uint2*)&Vt[((size_t)bb * H + h) * S + sBase + i * 16 + q4 * 4] =
            *(uint2*)pk;
      } else {
#pragma unroll
        for (int ii = 0; ii < 4; ++ii)
          Ob[i * 16 + q4 * 4 + ii][ncol + r16] = (bf16_t)acc[i][j][ii];
      }
    }
  __syncthreads();
  {
    int row = t >> 3, g = t & 7;
    bf16_t* qp = Qb + (size_t)(mBase + row) * H + g * 16;
    bf16_t* kp = Kb + (size_t)(mBase + row) * H + g * 16;
    *(uint4*)qp = *(uint4*)&Ob[row][g * 16];
    *(uint4*)(qp + 8) = *(uint4*)&Ob[row][g * 16 + 8];
    *(uint4*)kp = *(uint4*)&Ob[row][128 + g * 16];
    *(uint4*)(kp + 8) = *(uint4*)&Ob[row][128 + g * 16 + 8];
  }
#undef LOAD_X
#undef STAGE_W
#undef STAGE_X
#undef COMPUTE
#undef FENCE
#undef WAITB
}

// ---------------------------------------------------------------------------
// Kernel 3: flash attention partials. 512 blocks x 256 thr (2/CU); block =
// (b, qt, key-half): 64 q-rows x 1024 keys.  K/V double-buffered; stage
// it+1 issued before compute(it), drained by the end-of-iter barrier.
// Softmax: T13 defer-max (THR=8; lane-local partial max vs m_r, __all ->
// skip max-reduce + rescale entirely) and l-sum via MFMA P*ones (replaces
// the 4-deep shfl_xor sum chain).  Exact w.r.t. the merge step: m is only
// an exp offset; P bounded by e^8.
// ---------------------------------------------------------------------------
__global__ __launch_bounds__(256, 2) void attn_kernel(const bf16_t* __restrict__ Qb,
                                                      const bf16_t* __restrict__ Kb,
                                                      const bf16_t* __restrict__ Vt,
                                                      float* __restrict__ Op,
                                                      float* __restrict__ Mp,
                                                      float* __restrict__ Lp) {
  // buf0: K [0,16K) V [16K,32K) | buf1: K [32K,48K) V [48K,64K) | P [64K,73K)
  __shared__ __align__(16) char smem[74752];

  int bid = blockIdx.x;
  int b = bid & 7, r = bid >> 3;
  int qt = r >> 1, half = r & 1;

  int t = threadIdx.x, lane = t & 63, wl = t >> 6;
  int r16 = lane & 15, q4 = lane >> 4;
  bf16_t(*Pl)[72] = (bf16_t(*)[72])(smem + 65536 + wl * 2304);

  bf16x8 qf[4];
  {
    const bf16_t* qp = Qb + (size_t)(b * S + qt * 64 + wl * 16 + r16) * H + q4 * 8;
#pragma unroll
    for (int c = 0; c < 4; ++c) qf[c] = *(const bf16x8*)(qp + c * 32);
  }
  bf16x8 onef;
#pragma unroll
  for (int i = 0; i < 8; ++i) onef[i] = (bf16_t)1.0f;

  floatx4 o[8] = {};
  float m_r[4], l_r[4];
#pragma unroll
  for (int ii = 0; ii < 4; ++ii) { m_r[ii] = -1e30f; l_r[ii] = 0.f; }
  const float scale = 0.08838834764831845f;  // 1/sqrt(128)

  int kr = lane >> 4, kg = lane & 15;
  int vr = lane >> 3, vg = lane & 7;

#define STAGE_KV(BUF, KT)                                                        \
  _Pragma("unroll") for (int is = 0; is < 4; ++is) {                             \
    int row = wl * 16 + is * 4 + kr;                                             \
    int g = kg ^ (row & 15);                                                     \
    gl_lds16(Kb + (size_t)(b * S + (KT) * 64 + row) * H + g * 8,                 \
             smem + (BUF) + (wl * 16 + is * 4) * 256 + lane * 16);               \
  }                                                                              \
  _Pragma("unroll") for (int is = 0; is < 4; ++is) {                             \
    int row = wl * 32 + is * 8 + vr;                                             \
    int g = vg ^ (row & 7);                                                      \
    gl_lds16(Vt + (size_t)(b * H + row) * S + (KT) * 64 + g * 8,                 \
             smem + (BUF) + 16384 + (wl * 32 + is * 8) * 128 + lane * 16);       \
  }

  STAGE_KV(0, half * 16);
  __syncthreads();

  for (int it = 0; it < 16; ++it) {
    int cur = (it & 1) << 15;  // 0 or 32768
    if (it < 15) { STAGE_KV(cur ^ 32768, half * 16 + it + 1); }
    const char* kbase = smem + cur;
    bf16_t(*Vl)[64] = (bf16_t(*)[64])(smem + cur + 16384);

    // S = Q K^T   (Kl slot key = r16, conflict-free)
    floatx4 s4[4] = {};
    __builtin_amdgcn_s_setprio(1);
#pragma unroll
    for (int c = 0; c < 4; ++c)
#pragma unroll
      for (int j = 0; j < 4; ++j) {
        int row = j * 16 + r16;
        int sl = (c * 4 + q4) ^ r16;
        bf16x8 bk = *(const bf16x8*)(kbase + row * 256 + sl * 16);
        s4[j] = MFMA(qf[c], bk, s4[j]);
      }
    __builtin_amdgcn_s_setprio(0);

    // softmax, defer-max: lane-local partial max vs m_r + 8
    float p[4][4], mxl[4];
#pragma unroll
    for (int ii = 0; ii < 4; ++ii) mxl[ii] = -1e30f;
#pragma unroll
    for (int j = 0; j < 4; ++j)
#pragma unroll
      for (int ii = 0; ii < 4; ++ii) {
        float sv = s4[j][ii] * scale;
        p[j][ii] = sv;
        mxl[ii] = fmaxf(mxl[ii], sv);
      }
    int ok = 1;
#pragma unroll
    for (int ii = 0; ii < 4; ++ii) ok &= (mxl[ii] <= m_r[ii] + 8.f) ? 1 : 0;
    if (!__all(ok)) {
      // rare path: full max-reduce over the r16 group + rescale
      float alpha[4];
#pragma unroll
      for (int off = 1; off <= 8; off <<= 1)
#pragma unroll
        for (int ii = 0; ii < 4; ++ii)
          mxl[ii] = fmaxf(mxl[ii], __shfl_xor(mxl[ii], off));
#pragma unroll
      for (int ii = 0; ii < 4; ++ii) {
        float mn = fmaxf(m_r[ii], mxl[ii]);
        alpha[ii] = __expf(m_r[ii] - mn);
        m_r[ii] = mn;
        l_r[ii] *= alpha[ii];
      }
#pragma unroll
      for (int f = 0; f < 8; ++f)
#pragma unroll
        for (int ii = 0; ii < 4; ++ii) o[f][ii] *= alpha[ii];
    }
#pragma unroll
    for (int j = 0; j < 4; ++j)
#pragma unroll
      for (int ii = 0; ii < 4; ++ii) {
        float e = __expf(p[j][ii] - m_r[ii]);
        Pl[q4 * 4 + ii][j * 16 + r16] = (bf16_t)e;  // per-wave, in-order DS
      }

    // O += P V ; l += P * ones (MFMA row-sum, D-layout matches l_r[ii])
    bf16x8 pa0 = *(const bf16x8*)&Pl[r16][q4 * 8];
    bf16x8 pa1 = *(const bf16x8*)&Pl[r16][32 + q4 * 8];
    __builtin_amdgcn_s_setprio(1);
    floatx4 lsv = {};
    lsv = MFMA(pa0, onef, lsv);
    lsv = MFMA(pa1, onef, lsv);
#pragma unroll
    for (int f = 0; f < 8; ++f) {
      int row = f * 16 + r16;
      int sl = q4 ^ (row & 7);
      o[f] = MFMA(pa0, *(const bf16x8*)&Vl[row][sl * 8], o[f]);
    }
#pragma unroll
    for (int f = 0; f < 8; ++f) {
      int row = f * 16 + r16;
      int sl = (4 + q4) ^ (row & 7);
      o[f] = MFMA(pa1, *(const bf16x8*)&Vl[row][sl * 8], o[f]);
    }
    __builtin_amdgcn_s_setprio(0);
#pragma unroll
    for (int ii = 0; ii < 4; ++ii) l_r[ii] += lsv[ii];
    __syncthreads();
  }
#undef STAGE_KV

  // write unnormalized partials
  int rowg = b * S + qt * 64 + wl * 16 + q4 * 4;
  float* op = Op + ((size_t)half * 16384 + rowg) * 128;
#pragma unroll
  for (int f = 0; f < 8; ++f)
#pragma unroll
    for (int ii = 0; ii < 4; ++ii)
      op[ii * 128 + f * 16 + r16] = o[f][ii];
  if (r16 == 0) {
#pragma unroll
    for (int ii = 0; ii < 4; ++ii) {
      Mp[half * 16384 + rowg + ii] = m_r[ii];
      Lp[half * 16384 + rowg + ii] = l_r[ii];
    }
  }
}

// ---------------------------------------------------------------------------
// Kernel 4: merge the two key-half partials -> final output.
// ---------------------------------------------------------------------------
__global__ __launch_bounds__(256) void merge_kernel(const float* __restrict__ Op,
                                                    const float* __restrict__ Mp,
                                                    const float* __restrict__ Lp,
                                                    float* __restrict__ out) {
  int t = threadIdx.x;
  int row = blockIdx.x * 64 + (t >> 2);
  int c0 = (t & 3) * 32;
  float m1 = Mp[row], m2 = Mp[16384 + row];
  float l1 = Lp[row], l2 = Lp[16384 + row];
  float M = fmaxf(m1, m2);
  float e1 = __expf(m1 - M), e2 = __expf(m2 - M);
  float inv = 1.f / (e1 * l1 + e2 * l2);
  const float4* o1 = (const float4*)(Op + (size_t)row * 128 + c0);
  const float4* o2 = (const float4*)(Op + 16384ull * 128 + (size_t)row * 128 + c0);
  float4* op = (float4*)(out + (size_t)row * 128 + c0);
#pragma unroll
  for (int i = 0; i < 8; ++i) {
    float4 a = o1[i], b = o2[i];
    float4 rr;
    rr.x = (e1 * a.x + e2 * b.x) * inv;
    rr.y = (e1 * a.y + e2 * b.y) * inv;
    rr.z = (e1 * a.z + e2 * b.z) * inv;
    rr.w = (e1 * a.w + e2 * b.w) * inv;
    op[i] = rr;
  }
}

// ---------------------------------------------------------------------------
extern "C" void kernel_launch(void* const* d_in, const int* in_sizes, int n_in,
                              void* d_out, int out_size, void* d_ws, size_t ws_size,
                              hipStream_t stream) {
  const float* x = (const float*)d_in[0];
  const float* Wq = (const float*)d_in[1];
  const float* Wk = (const float*)d_in[2];
  const float* Wv = (const float*)d_in[3];
  float* out = (float*)d_out;

  // ws (bf16): Wt [384][4096] | Qb [16384][128] | Kb | Vt [8][128][2048]
  // then (f32): Op [2][16384][128] | Mp [2][16384] | Lp [2][16384]
  bf16_t* Wt = (bf16_t*)d_ws;
  bf16_t* Qb = Wt + (size_t)384 * 4096;
  bf16_t* Kb = Qb + (size_t)16384 * 128;
  bf16_t* Vt = Kb + (size_t)16384 * 128;
  float* Op = (float*)(Vt + (size_t)8 * 128 * 2048);
  float* Mp = Op + (size_t)2 * 16384 * 128;
  float* Lp = Mp + 2 * 16384;

  wt_kernel<<<192, 256, 0, stream>>>(Wq, Wk, Wv, Wt);
  qkv_kernel<<<256, 512, 0, stream>>>(x, Wt, Qb, Kb, Vt);
  attn_kernel<<<512, 256, 0, stream>>>(Qb, Kb, Vt, Op, Mp, Lp);
  merge_kernel<<<256, 256, 0, stream>>>(Op, Mp, Lp, out);
}